// Round 13
// baseline (476.403 us; speedup 1.0000x reference)
//
#include <hip/hip_runtime.h>
#include <math.h>

// Problem constants
#define C_DIM 64
#define T_DIM 256
#define F_DIM 128
#define DI    128
#define DS    16
#define CK    32     // tokens per chunk (512-thread k_mamba)

typedef __attribute__((ext_vector_type(8))) short bf16x8;  // 8 bf16 = 4 VGPRs
typedef __attribute__((ext_vector_type(4))) float f32x4;   // MFMA C/D

__device__ __forceinline__ float silu_f(float v){ return v / (1.0f + __expf(-v)); }

__device__ __forceinline__ unsigned short f2bf(float f){
  union{float f; unsigned u;} v; v.f = f;
  unsigned r = v.u + 0x7FFFu + ((v.u >> 16) & 1u);   // RTNE
  return (unsigned short)(r >> 16);
}

// XOR-swizzle (ushort units, 16B granule). Same transform write+read.
__device__ __forceinline__ int swz64(int row, int col){   // rows of 64 ushorts
  return row*64 + (col ^ ((row & 7) << 3));
}
__device__ __forceinline__ int swz128(int row, int col){  // rows of 128 ushorts
  return row*128 + (col ^ ((row & 7) << 3));
}

// ---------------------------------------------------------------------------
// bf16 weight prep into d_out scratch (fully overwritten by k_final later):
//   [0,65536)        in_proj   [4][256][64]
//   [65536,98304)    out_proj  [4][64][128]
//   [98304,122880)   x_proj    [4][48][128]  rows 36..47 zero-padded
//   [122880,131072)  tlin^T    [64][128]
// ---------------------------------------------------------------------------
__global__ __launch_bounds__(256) void k_prep(const float* __restrict__ ipw,
                                              const float* __restrict__ opw,
                                              const float* __restrict__ xpw,
                                              const float* __restrict__ tlw,
                                              unsigned short* __restrict__ wbuf){
  const int i = blockIdx.x*256 + threadIdx.x;
  if(i < 65536){
    wbuf[i] = f2bf(ipw[i]);
  } else if(i < 98304){
    wbuf[i] = f2bf(opw[i - 65536]);
  } else if(i < 122880){
    const int j = i - 98304;
    const int p = j / 6144, rr = (j - p*6144) >> 7, k = j & 127;
    wbuf[i] = (rr < 36) ? f2bf(xpw[p*4608 + rr*128 + k]) : (unsigned short)0;
  } else { // i < 131072
    const int j = i - 122880;
    const int o = j >> 7, k = j & 127;
    wbuf[i] = f2bf(tlw[k*64 + o]);
  }
}

// ---------------------------------------------------------------------------
// x (1,64,256,128) [c,t,f] -> xt (f,t,c), one block per t
// ---------------------------------------------------------------------------
__global__ __launch_bounds__(256) void k_transpose_in(const float* __restrict__ x,
                                                      float* __restrict__ xt){
  __shared__ float tile[64][133];
  const int t = blockIdx.x;
  {
    const int fi = threadIdx.x & 127, cg = threadIdx.x >> 7;
    for(int c = cg*32; c < cg*32 + 32; ++c)
      tile[c][fi] = x[(size_t)c*32768 + (size_t)t*128 + fi];
  }
  __syncthreads();
  {
    const int ci = threadIdx.x & 63, fg = threadIdx.x >> 6;
    for(int f = fg*32; f < fg*32 + 32; ++f)
      xt[(size_t)f*16384 + (size_t)t*64 + ci] = tile[ci][f];
  }
}

// ---------------------------------------------------------------------------
// Fused per-sequence Mamba mixer: 512 threads (8 waves), CK=32.
// Sections per chunk (6 barriers): A:[shift,P1,P8b(prev)] B:[P2] C:[P3]
// D:[P4] E:[dt+scan+gate] F:[P8].  zy = union(z gate, y_out staging).
// ---------------------------------------------------------------------------
__global__ __launch_bounds__(512, 4) void k_mamba(
    const float* __restrict__ src, int N, int L, long long sn, long long sl,
    int pbase,
    const float* __restrict__ norm_w,   const unsigned short* __restrict__ wbf,
    const float* __restrict__ conv_w,   const float* __restrict__ conv_b,
    const float* __restrict__ dt_proj_w,
    const float* __restrict__ dt_proj_b,const float* __restrict__ A_log,
    const float* __restrict__ Dp,       float* __restrict__ obuf)
{
  __shared__ __align__(16) unsigned short u_bf[CK*64];    // swz64
  __shared__ __align__(16) float x_s[CK+3][132];          // conv in, 0..2 hist
  __shared__ __align__(16) float zy[CK][132];             // z gate / y_out
  __shared__ __align__(16) float xc_s[CK][132];           // conv out fp32
  __shared__ __align__(16) unsigned short xc_bf[CK*128];  // swz128
  __shared__ __align__(16) float dtr_s[CK][4];
  __shared__ __align__(16) float B_s[CK][20];
  __shared__ __align__(16) float C_s[CK][20];
  __shared__ __align__(16) unsigned short y_bf[CK*128];   // swz128
  __shared__ float w_cv[512];
  __shared__ float b_cv[128];
  __shared__ float nw[64];

  const int tid = threadIdx.x;
  const int bid = blockIdx.x;
  const int dir = (bid >= N) ? 1 : 0;
  const int n   = dir ? (bid - N) : bid;
  const int p   = pbase + dir;

  const int lane = tid & 63;
  const int wv   = tid >> 6;          // wave 0..7
  const int fr   = lane & 15;
  const int fk   = (lane >> 4) << 3;  // {0,8,16,24}

  if(tid < 512) w_cv[tid] = conv_w[p*512 + tid];
  if(tid < 128) b_cv[tid] = conv_b[p*128 + tid];
  if(tid < 64)  nw[tid]   = norm_w[p*64 + tid];
  if(tid < 384) x_s[tid >> 7][tid & 127] = 0.0f;   // zero conv history

  // MFMA weight fragments.
  const unsigned short* WinB  = wbf + (size_t)p*16384;          // [256][64]
  const unsigned short* WoutB = wbf + 65536 + (size_t)p*8192;   // [64][128]
  const unsigned short* XpB   = wbf + 98304 + (size_t)p*6144;   // [48][128]
  // P2: wave wv -> o-tiles {2wv, 2wv+1} (o = 32wv .. 32wv+31)
  bf16x8 aW[2][2];
  #pragma unroll
  for(int j = 0; j < 2; ++j)
    #pragma unroll
    for(int kh = 0; kh < 2; ++kh)
      aW[j][kh] = *(const bf16x8*)(WinB + ((2*wv + j)*16 + fr)*64 + kh*32 + fk);
  // P8: wave wv -> (ot = wv>>1, tt = wv&1)
  bf16x8 aO[4];
  {
    const int ot = wv >> 1;
    #pragma unroll
    for(int kc = 0; kc < 4; ++kc)
      aO[kc] = *(const bf16x8*)(WoutB + (ot*16 + fr)*128 + kc*32 + fk);
  }
  // P4: waves 0..5 -> (ot3 = wv>>1, tt = wv&1)
  bf16x8 aXP[4];
  if(wv < 6){
    const int ot3 = wv >> 1;
    #pragma unroll
    for(int kc = 0; kc < 4; ++kc)
      aXP[kc] = *(const bf16x8*)(XpB + (ot3*16 + fr)*128 + kc*32 + fk);
  }

  // scan state: 4 threads per channel d (quad-split over 16 states)
  const int d_own = tid >> 2;          // 0..127
  const int q     = tid & 3;           // state quad / token octet
  const int sh    = q * 4;
  const float4 wdt4  = *(const float4*)(dt_proj_w + p*512 + d_own*4);
  const float  bdt_r = dt_proj_b[p*128 + d_own];
  const float  dvec_r= Dp[p*128 + d_own];
  float A_r[4], h[4];
  #pragma unroll
  for(int i = 0; i < 4; ++i){
    A_r[i] = -__expf(A_log[p*2048 + d_own*16 + sh + i]) * 1.44269504f;
    h[i] = 0.0f;
  }
  __syncthreads();

  for(int c0 = 0; c0 < L; c0 += CK){
    // ---- sec A: history shift + P1 load/norm + P8b store of prev chunk ----
    if(c0 > 0){
      if(tid < 384){
        const int r = tid >> 7, ch = tid & 127;
        x_s[r][ch] = x_s[CK + r][ch];
      }
      // P8b: store prev chunk's y_out (zy cols 0..63)
      const int token = tid >> 4, c4 = (tid & 15) * 4;
      const int l = (c0 - CK) + token;
      const int lo = dir ? (L - 1 - l) : l;
      const float4 v = *(const float4*)&zy[token][c4];
      *(float4*)(obuf + ((size_t)dir*32768 + (size_t)n*L + lo)*64 + c4) = v;
    }
    {
      // P1: 32 tokens x 16 threads
      const int g = tid >> 4, j = tid & 15, c4 = j*4;
      const int l = c0 + g;
      const int lo = dir ? (L - 1 - l) : l;
      const float4 v = *(const float4*)(src + (size_t)n*sn + (size_t)lo*sl + c4);
      float ssq = v.x*v.x + v.y*v.y + v.z*v.z + v.w*v.w;
      ssq += __shfl_xor(ssq, 1); ssq += __shfl_xor(ssq, 2);
      ssq += __shfl_xor(ssq, 4); ssq += __shfl_xor(ssq, 8);
      const float sc = rsqrtf(ssq * (1.0f/64.0f) + 1e-5f);
      ushort4 pk;
      pk.x = f2bf(v.x * sc * nw[c4+0]);
      pk.y = f2bf(v.y * sc * nw[c4+1]);
      pk.z = f2bf(v.z * sc * nw[c4+2]);
      pk.w = f2bf(v.w * sc * nw[c4+3]);
      *(ushort4*)&u_bf[swz64(g, c4)] = pk;
    }
    __syncthreads();

    // ---- sec B: P2 in_proj 64->256, 8 waves x (2 o-tiles x 2 token-tiles) --
    {
      #pragma unroll
      for(int tt = 0; tt < 2; ++tt){
        const bf16x8 b0 = *(const bf16x8*)&u_bf[swz64(tt*16 + fr, fk)];
        const bf16x8 b1 = *(const bf16x8*)&u_bf[swz64(tt*16 + fr, 32 + fk)];
        #pragma unroll
        for(int j = 0; j < 2; ++j){
          f32x4 acc = {0.f, 0.f, 0.f, 0.f};
          acc = __builtin_amdgcn_mfma_f32_16x16x32_bf16(aW[j][0], b0, acc, 0, 0, 0);
          acc = __builtin_amdgcn_mfma_f32_16x16x32_bf16(aW[j][1], b1, acc, 0, 0, 0);
          const int o  = (2*wv + j)*16 + ((lane >> 4) << 2);
          const int tk = tt*16 + fr;
          if(wv < 4){
            #pragma unroll
            for(int r = 0; r < 4; ++r) x_s[3 + tk][o + r] = acc[r];
          } else {
            #pragma unroll
            for(int r = 0; r < 4; ++r) zy[tk][o + r - 128] = acc[r];
          }
        }
      }
    }
    __syncthreads();

    // ---- sec C: P3 conv + bias + silu -> xc_s, xc_bf ----
    {
      const int g = tid >> 4, j = tid & 15;
      #pragma unroll
      for(int i = 0; i < 8; ++i){
        const int ch = j + 16*i;
        float a = b_cv[ch];
        a += w_cv[ch*4+0] * x_s[g+0][ch];
        a += w_cv[ch*4+1] * x_s[g+1][ch];
        a += w_cv[ch*4+2] * x_s[g+2][ch];
        a += w_cv[ch*4+3] * x_s[g+3][ch];
        const float s = silu_f(a);
        xc_s[g][ch] = s;
        xc_bf[swz128(g, ch)] = f2bf(s);
      }
    }
    __syncthreads();

    // ---- sec D: P4 x_proj 128->36, waves 0..5 ----
    if(wv < 6){
      const int tt = wv & 1;
      f32x4 acc = {0.f, 0.f, 0.f, 0.f};
      #pragma unroll
      for(int kc = 0; kc < 4; ++kc){
        const bf16x8 b = *(const bf16x8*)&xc_bf[swz128(tt*16 + fr, kc*32 + fk)];
        acc = __builtin_amdgcn_mfma_f32_16x16x32_bf16(aXP[kc], b, acc, 0, 0, 0);
      }
      const int ob36 = (wv >> 1)*16 + ((lane >> 4) << 2);
      const int tk = tt*16 + fr;
      #pragma unroll
      for(int r = 0; r < 4; ++r){
        const int o36 = ob36 + r;
        const float v = acc[r];
        if(o36 < 4)       dtr_s[tk][o36] = v;
        else if(o36 < 20) B_s[tk][o36 - 4] = v;
        else if(o36 < 36) C_s[tk][o36 - 20] = v;
      }
    }
    __syncthreads();

    // ---- sec E: dt (quad-split) + scan + gating -> y_bf ----
    {
      float my_dt[8];
      #pragma unroll
      for(int m = 0; m < 8; ++m){
        const int l = q*8 + m;
        const float4 r4 = *(const float4*)&dtr_s[l][0];
        float a = bdt_r + wdt4.x*r4.x + wdt4.y*r4.y + wdt4.z*r4.z + wdt4.w*r4.w;
        my_dt[m] = fmaxf(a, 0.0f) + log1pf(__expf(-fabsf(a)));  // softplus
      }
      const int gbase = lane & ~3;
      #pragma unroll
      for(int l = 0; l < CK; ++l){
        const float dtv = __shfl(my_dt[l & 7], gbase | (l >> 3));
        const float xv  = xc_s[l][d_own];
        const float4 b4 = *(const float4*)&B_s[l][sh];
        const float4 c4v= *(const float4*)&C_s[l][sh];
        const float bb[4] = {b4.x, b4.y, b4.z, b4.w};
        const float cc[4] = {c4v.x, c4v.y, c4v.z, c4v.w};
        const float dx = dtv * xv;
        float yp = 0.0f;
        #pragma unroll
        for(int i = 0; i < 4; ++i){
          h[i] = exp2f(dtv * A_r[i]) * h[i] + dx * bb[i];
          yp += h[i] * cc[i];
        }
        yp += __shfl_xor(yp, 1);
        yp += __shfl_xor(yp, 2);
        if(q == 0){
          const float zv = zy[l][d_own];
          y_bf[swz128(l, d_own)] = f2bf((yp + xv * dvec_r) * silu_f(zv));
        }
      }
    }
    __syncthreads();

    // ---- sec F: P8 out_proj 128->64 via MFMA -> zy (y_out cols 0..63) ----
    {
      const int tt = wv & 1;
      f32x4 acc = {0.f, 0.f, 0.f, 0.f};
      #pragma unroll
      for(int kc = 0; kc < 4; ++kc){
        const bf16x8 b = *(const bf16x8*)&y_bf[swz128(tt*16 + fr, kc*32 + fk)];
        acc = __builtin_amdgcn_mfma_f32_16x16x32_bf16(aO[kc], b, acc, 0, 0, 0);
      }
      const int o2 = (wv >> 1)*16 + ((lane >> 4) << 2);
      const int tk = tt*16 + fr;
      #pragma unroll
      for(int r = 0; r < 4; ++r) zy[tk][o2 + r] = acc[r];
    }
    __syncthreads();
  }
  // epilogue: store last chunk's y_out
  {
    const int token = tid >> 4, c4 = (tid & 15) * 4;
    const int l = (L - CK) + token;
    const int lo = dir ? (L - 1 - l) : l;
    const float4 v = *(const float4*)&zy[token][c4];
    *(float4*)(obuf + ((size_t)dir*32768 + (size_t)n*L + lo)*64 + c4) = v;
  }
}

// ---------------------------------------------------------------------------
// xt2 = xt + (of+xt)@tlin[0:64] + (ob+xt)@tlin[64:128] + tlin_b  via MFMA.
// ---------------------------------------------------------------------------
__global__ __launch_bounds__(256) void k_comb_time(
    const float* __restrict__ xt, const float* __restrict__ obuf,
    const unsigned short* __restrict__ wbf, const float* __restrict__ tlin_b,
    float* __restrict__ xt2)
{
  __shared__ __align__(16) unsigned short in_bf[64][128];
  __shared__ float xs[64][72];
  const int tid = threadIdx.x;
  const int lane = tid & 63, wv = tid >> 6;
  const int fr = lane & 15, fk = (lane >> 4) << 3;
  const int tk0 = blockIdx.x*64;

  const unsigned short* TL = wbf + 122880;
  bf16x8 aT[4];
  #pragma unroll
  for(int kc = 0; kc < 4; ++kc)
    aT[kc] = *(const bf16x8*)(TL + (wv*16 + fr)*128 + kc*32 + fk);

  {
    const int tg = tid >> 2, q = tid & 3;
    #pragma unroll
    for(int s = 0; s < 4; ++s){
      const int c4 = q*16 + s*4;
      const float4 xv = *(const float4*)(xt   + ((size_t)tk0 + tg)*64 + c4);
      const float4 fv = *(const float4*)(obuf + ((size_t)tk0 + tg)*64 + c4);
      const float4 bv = *(const float4*)(obuf + ((size_t)32768 + tk0 + tg)*64 + c4);
      ushort4 pf, pb;
      pf.x = f2bf(fv.x + xv.x); pf.y = f2bf(fv.y + xv.y);
      pf.z = f2bf(fv.z + xv.z); pf.w = f2bf(fv.w + xv.w);
      pb.x = f2bf(bv.x + xv.x); pb.y = f2bf(bv.y + xv.y);
      pb.z = f2bf(bv.z + xv.z); pb.w = f2bf(bv.w + xv.w);
      *(ushort4*)&in_bf[tg][c4]      = pf;
      *(ushort4*)&in_bf[tg][64 + c4] = pb;
      *(float4*)&xs[tg][c4] = xv;
    }
  }
  __syncthreads();

  {
    const int ob = wv*16 + ((lane >> 4) << 2);
    const float4 tb = *(const float4*)(tlin_b + ob);
    const float tbr[4] = {tb.x, tb.y, tb.z, tb.w};
    #pragma unroll
    for(int tt = 0; tt < 4; ++tt){
      f32x4 acc = {0.f, 0.f, 0.f, 0.f};
      #pragma unroll
      for(int kc = 0; kc < 4; ++kc){
        const bf16x8 b = *(const bf16x8*)&in_bf[tt*16 + fr][kc*32 + fk];
        acc = __builtin_amdgcn_mfma_f32_16x16x32_bf16(aT[kc], b, acc, 0, 0, 0);
      }
      const int token = tt*16 + fr;
      #pragma unroll
      for(int r = 0; r < 4; ++r)
        xs[token][ob + r] += tbr[r] + acc[r];
    }
  }
  __syncthreads();

  {
    const int tg = tid >> 2, q = tid & 3;
    #pragma unroll
    for(int s = 0; s < 4; ++s){
      const int c4 = q*16 + s*4;
      *(float4*)(xt2 + ((size_t)tk0 + tg)*64 + c4) = *(const float4*)&xs[tg][c4];
    }
  }
}

// ---------------------------------------------------------------------------
// Final: xf2 = xf + (of+xf)@flin[0:64] + (ob+xf)@flin[64:128] + flin_b,
// then transposed store out[c,t,f]. One block per t; thread pair per f.
// ---------------------------------------------------------------------------
__global__ __launch_bounds__(256) void k_final(
    const float* __restrict__ xt2, const float* __restrict__ obuf,
    const float* __restrict__ flin_w, const float* __restrict__ flin_b,
    float* __restrict__ out)
{
  __shared__ float res_s[128][68];
  const int t = blockIdx.x, tid = threadIdx.x;
  const int f = tid >> 1, half = tid & 1, cbase = half*32;

  const float4* xr = (const float4*)(xt2  + (size_t)f*16384 + (size_t)t*64);
  const float4* fr = (const float4*)(obuf + ((size_t)t*128 + f)*64);
  const float4* br = (const float4*)(obuf + ((size_t)32768 + (size_t)t*128 + f)*64);

  float res[32];
  {
    const float4* fb = (const float4*)(flin_b + cbase);
    #pragma unroll
    for(int q = 0; q < 8; ++q){
      const float4 xv = xr[(cbase >> 2) + q], b = fb[q];
      res[q*4+0] = xv.x + b.x; res[q*4+1] = xv.y + b.y;
      res[q*4+2] = xv.z + b.z; res[q*4+3] = xv.w + b.w;
    }
  }
  for(int i4 = 0; i4 < 16; ++i4){
    const float4 xv4 = xr[i4], of4 = fr[i4], ob4 = br[i4];
    const float af[4] = {of4.x + xv4.x, of4.y + xv4.y, of4.z + xv4.z, of4.w + xv4.w};
    const float ab[4] = {ob4.x + xv4.x, ob4.y + xv4.y, ob4.z + xv4.z, ob4.w + xv4.w};
    #pragma unroll
    for(int ii = 0; ii < 4; ++ii){
      const int i = i4*4 + ii;
      const float4* F0 = (const float4*)(flin_w + i*64 + cbase);
      const float4* F1 = (const float4*)(flin_w + (64 + i)*64 + cbase);
      #pragma unroll
      for(int q = 0; q < 8; ++q){
        const float4 w0 = F0[q], w1 = F1[q];
        res[q*4+0] += af[ii]*w0.x + ab[ii]*w1.x;
        res[q*4+1] += af[ii]*w0.y + ab[ii]*w1.y;
        res[q*4+2] += af[ii]*w0.z + ab[ii]*w1.z;
        res[q*4+3] += af[ii]*w0.w + ab[ii]*w1.w;
      }
    }
  }
  #pragma unroll
  for(int c = 0; c < 32; ++c) res_s[f][cbase + c] = res[c];
  __syncthreads();
  {
    const int fi = tid & 127, cq = tid >> 7;
    for(int c = cq*32; c < cq*32 + 32; ++c)
      out[(size_t)c*32768 + (size_t)t*128 + fi] = res_s[fi][c];
  }
}

// ---------------------------------------------------------------------------
extern "C" void kernel_launch(void* const* d_in, const int* in_sizes, int n_in,
                              void* d_out, int out_size, void* d_ws, size_t ws_size,
                              hipStream_t stream){
  (void)in_sizes; (void)n_in; (void)out_size; (void)ws_size;
  const float* x         = (const float*)d_in[0];
  const float* norm_w    = (const float*)d_in[1];
  const float* in_proj_w = (const float*)d_in[2];
  const float* conv_w    = (const float*)d_in[3];
  const float* conv_b    = (const float*)d_in[4];
  const float* x_proj_w  = (const float*)d_in[5];
  const float* dt_proj_w = (const float*)d_in[6];
  const float* dt_proj_b = (const float*)d_in[7];
  const float* A_log     = (const float*)d_in[8];
  const float* Dp        = (const float*)d_in[9];
  const float* out_proj_w= (const float*)d_in[10];
  const float* tlin_w    = (const float*)d_in[11];
  const float* tlin_b    = (const float*)d_in[12];
  const float* flin_w    = (const float*)d_in[13];
  const float* flin_b    = (const float*)d_in[14];
  float* out = (float*)d_out;

  float* xt_buf = (float*)d_ws;                 // 2M floats  (8 MB)   [f][t][c]
  float* obuf   = xt_buf + (size_t)(1u << 21);  // 4M floats  (16 MB)  [dir][token][64]
  float* xt2    = obuf   + (size_t)(1u << 22);  // 2M floats  (8 MB)   [f][t][c]

  unsigned short* wbf = (unsigned short*)d_out; // scratch; k_final overwrites

  hipLaunchKernelGGL(k_prep, dim3(512), dim3(256), 0, stream,
      in_proj_w, out_proj_w, x_proj_w, tlin_w, wbf);

  hipLaunchKernelGGL(k_transpose_in, dim3(256), dim3(256), 0, stream, x, xt_buf);

  // time axis: N=128 sequences (f), L=256 (t); params P0 (fwd), P1 (bwd)
  hipLaunchKernelGGL(k_mamba, dim3(256), dim3(512), 0, stream,
      xt_buf, 128, 256, (long long)16384, (long long)64, 0,
      norm_w, wbf, conv_w, conv_b, dt_proj_w, dt_proj_b,
      A_log, Dp, obuf);

  hipLaunchKernelGGL(k_comb_time, dim3(512), dim3(256), 0, stream,
      xt_buf, obuf, wbf, tlin_b, xt2);

  // freq axis: N=256 sequences (t), L=128 (f); params P2 (fwd), P3 (bwd)
  hipLaunchKernelGGL(k_mamba, dim3(512), dim3(512), 0, stream,
      xt2, 256, 128, (long long)64, (long long)16384, 2,
      norm_w, wbf, conv_w, conv_b, dt_proj_w, dt_proj_b,
      A_log, Dp, obuf);

  hipLaunchKernelGGL(k_final, dim3(256), dim3(256), 0, stream,
      xt2, obuf, flin_w, flin_b, out);
}